// Round 21
// baseline (140.224 us; speedup 1.0000x reference)
//
#include <hip/hip_runtime.h>
#include <math.h>

#define Bsz 4
#define Lq  1024
#define Emb 1024
#define Hh  16
#define Dd  64

typedef short bf16x8 __attribute__((ext_vector_type(8)));
typedef float f32x4 __attribute__((ext_vector_type(4)));

static __device__ __forceinline__ unsigned short f2bf(float f) {
    unsigned u = __float_as_uint(f);
    return (unsigned short)((u + 0x7FFFu + ((u >> 16) & 1u)) >> 16);
}
// pack two f32 -> two bf16 (round-half-up) in one v_perm
static __device__ __forceinline__ unsigned pack2(float lo, float hi) {
    return __builtin_amdgcn_perm(__float_as_uint(hi) + 0x8000u,
                                 __float_as_uint(lo) + 0x8000u, 0x07060302u);
}

// cross-fg reduces (lanes {l, l^16, l^32, l^48}); proven-correct shfl form.
static __device__ __forceinline__ float cross_max(float x) {
    x = fmaxf(x, __shfl_xor(x, 16, 64));
    x = fmaxf(x, __shfl_xor(x, 32, 64));
    return x;
}
static __device__ __forceinline__ float cross_sum(float x) {
    x += __shfl_xor(x, 16, 64);
    x += __shfl_xor(x, 32, 64);
    return x;
}

// global -> LDS direct copy, 16 B per lane.
#define GLOAD_LDS16(gp, lp) __builtin_amdgcn_global_load_lds(                  \
    (const __attribute__((address_space(1))) void*)(gp),                       \
    (__attribute__((address_space(3))) void*)(lp), 16, 0, 0)

// ---------------------------------------------------------------------------
// One launch: converts q,k,v (3 x 1048576 float4) + 4 weights (4 x 262144)
// and computes the mask bias (blocks >= 16384).
__global__ __launch_bounds__(256) void cvt_all(const float* __restrict__ q,
                                               const float* __restrict__ k,
                                               const float* __restrict__ v,
                                               const float* __restrict__ w0,
                                               const float* __restrict__ w1,
                                               const float* __restrict__ w2,
                                               const float* __restrict__ w3,
                                               unsigned short* __restrict__ qo,
                                               unsigned short* __restrict__ ko,
                                               unsigned short* __restrict__ vo,
                                               unsigned short* __restrict__ o0,
                                               unsigned short* __restrict__ o1,
                                               unsigned short* __restrict__ o2,
                                               unsigned short* __restrict__ o3,
                                               const float* __restrict__ mask,
                                               const int* __restrict__ kpm,
                                               float* __restrict__ bias)
{
    if (blockIdx.x >= 16384) {
        int i = (blockIdx.x - 16384) * 256 + threadIdx.x;   // 0..4095
        float bv = 8.0f * logf(fmaxf(mask[i], 1e-6f));
        bias[i] = kpm[i] ? -INFINITY : bv;
        return;
    }
    int i = blockIdx.x * 256 + threadIdx.x;
    const float* src; unsigned short* dst; int off;
    if (i < 1048576)      { src = q; dst = qo; off = i; }
    else if (i < 2097152) { src = k; dst = ko; off = i - 1048576; }
    else if (i < 3145728) { src = v; dst = vo; off = i - 2097152; }
    else {
        int j = i - 3145728;
        int reg = j >> 18; off = j & 262143;
        src = (reg == 0) ? w0 : (reg == 1) ? w1 : (reg == 2) ? w2 : w3;
        dst = (reg == 0) ? o0 : (reg == 1) ? o1 : (reg == 2) ? o2 : o3;
    }
    float4 x = ((const float4*)src)[off];
    ushort4 o;
    o.x = f2bf(x.x); o.y = f2bf(x.y); o.z = f2bf(x.z); o.w = f2bf(x.w);
    ((ushort4*)dst)[off] = o;
}

// ---------------------------------------------------------------------------
// Fused Q/K/V projections, 128x128 tile (r6-validated geometry) with r12's
// stage-ahead dbuf + XOR swizzle.  4 waves x 64x64 subtile, 32 MFMA per wave
// per K-step against one barrier drain.  Q pre-scaled by 0.125.
// Grid 768: which = bid>>8; per which 256 blocks, XCD-swizzled 4 bm x 8 bn.
// ---------------------------------------------------------------------------
__global__ __launch_bounds__(256) void gemm_qkv(const unsigned short* __restrict__ Aq,
                                                const unsigned short* __restrict__ Ak,
                                                const unsigned short* __restrict__ Av,
                                                const unsigned short* __restrict__ Wq,
                                                const unsigned short* __restrict__ Wk,
                                                const unsigned short* __restrict__ Wv,
                                                const float* __restrict__ biq,
                                                const float* __restrict__ bik,
                                                const float* __restrict__ biv,
                                                unsigned short* __restrict__ Oq,
                                                unsigned short* __restrict__ Ok,
                                                unsigned short* __restrict__ Ov)
{
    const int K = 1024;
    __shared__ unsigned short sA[2][128][64];   // 32 KB  dbuf, swizzled
    __shared__ unsigned short sB[2][128][64];   // 32 KB  dbuf, swizzled
    int tid = threadIdx.x;
    int w = tid >> 6, lane = tid & 63;

    int bid = blockIdx.x;
    int which = bid >> 8;              // 0=Q 1=K 2=V
    int lin = bid & 255;
    int xcd = lin & 7, idx = lin >> 3; // idx in [0,32)
    int bm = (xcd * 4 + (idx >> 3)) * 128;
    int bn = (idx & 7) * 128;

    const unsigned short* A = (which == 0) ? Aq : (which == 1) ? Ak : Av;
    const unsigned short* Bw = (which == 0) ? Wq : (which == 1) ? Wk : Wv;
    const float* bias = (which == 0) ? biq : (which == 1) ? bik : biv;
    unsigned short* outp = (which == 0) ? Oq : (which == 1) ? Ok : Ov;

    int wr = (w >> 1) * 64, wc = (w & 1) * 64;
    int fr = lane & 15, fg = lane >> 4;
    int csw = fr & 7;                  // read-side XOR on col16 unit

    int srl = lane >> 3;               // 0..7
    int scb = (lane & 7) ^ srl;        // pre-swizzled col16 on stage

    const unsigned short* Ag = A + (size_t)(bm + w * 32 + srl) * K + scb * 8;
    const unsigned short* Bg = Bw + (size_t)(bn + w * 32 + srl) * K + scb * 8;

#define STAGE(BUF, K0) do {                                                      \
    _Pragma("unroll")                                                            \
    for (int j = 0; j < 4; ++j)                                                  \
        GLOAD_LDS16(Ag + (size_t)j * 8 * K + (K0), &sA[BUF][w * 32 + j * 8][0]); \
    _Pragma("unroll")                                                            \
    for (int j = 0; j < 4; ++j)                                                  \
        GLOAD_LDS16(Bg + (size_t)j * 8 * K + (K0), &sB[BUF][w * 32 + j * 8][0]); \
} while (0)

    f32x4 acc[4][4];
#pragma unroll
    for (int i = 0; i < 4; ++i)
#pragma unroll
        for (int j = 0; j < 4; ++j) acc[i][j] = (f32x4){0.f, 0.f, 0.f, 0.f};

    STAGE(0, 0);
    __syncthreads();

#pragma unroll 1
    for (int k0 = 0; k0 < K; k0 += 64) {
        int cur = (k0 >> 6) & 1;
        if (k0 + 64 < K) STAGE(cur ^ 1, k0 + 64);
        bf16x8 af[4][2], bfv[4][2];
#pragma unroll
        for (int i = 0; i < 4; ++i)
#pragma unroll
            for (int kk = 0; kk < 2; ++kk)
                af[i][kk] = *(const bf16x8*)&sA[cur][wr + i * 16 + fr][((kk * 4 + fg) ^ csw) * 8];
#pragma unroll
        for (int j = 0; j < 4; ++j)
#pragma unroll
            for (int kk = 0; kk < 2; ++kk)
                bfv[j][kk] = *(const bf16x8*)&sB[cur][wc + j * 16 + fr][((kk * 4 + fg) ^ csw) * 8];
        __builtin_amdgcn_s_setprio(1);
#pragma unroll
        for (int i = 0; i < 4; ++i)
#pragma unroll
            for (int j = 0; j < 4; ++j) {
                acc[i][j] = __builtin_amdgcn_mfma_f32_16x16x32_bf16(af[i][0], bfv[j][0], acc[i][j], 0, 0, 0);
                acc[i][j] = __builtin_amdgcn_mfma_f32_16x16x32_bf16(af[i][1], bfv[j][1], acc[i][j], 0, 0, 0);
            }
        __builtin_amdgcn_s_setprio(0);
        __syncthreads();
    }
#undef STAGE

    int rb = (lane >> 4) * 4;
    float osc = (which == 0) ? 0.125f : 1.0f;   // fold QK^T scale into Q
#pragma unroll
    for (int j = 0; j < 4; ++j) {
        int n = bn + wc + j * 16 + fr;
        float bia = bias[n];
#pragma unroll
        for (int i = 0; i < 4; ++i) {
#pragma unroll
            for (int r = 0; r < 4; ++r) {
                int m = bm + wr + i * 16 + rb + r;
                float v = (acc[i][j][r] + bia) * osc;
                int b = m >> 10, l = m & 1023, h = n >> 6, d = n & 63;
                if (which == 2)
                    outp[(((size_t)(b * Hh + h)) * Dd + d) * Lq + l] = f2bf(v);
                else
                    outp[(((size_t)(b * Hh + h)) * Lq + l) * Dd + d] = f2bf(v);
            }
        }
    }
}

// ---------------------------------------------------------------------------
// Pass C: flash attention (r20-validated: bias-in-accumulator, pre-scaled Q,
// setprio around MFMA clusters, deferred l).
// ---------------------------------------------------------------------------
__global__ __launch_bounds__(256) void attn_flash(const unsigned short* __restrict__ Qh,
                                                  const unsigned short* __restrict__ Kh,
                                                  const unsigned short* __restrict__ Vt,
                                                  const float* __restrict__ mbias,
                                                  unsigned short* __restrict__ ctx,
                                                  float* __restrict__ mstats,
                                                  float* __restrict__ lstats)
{
    __shared__ float sBias[1024];                 // 4 KB
    __shared__ unsigned short Wl[4][2][16][64];   // 16 KB  per-wave P tiles
    __shared__ unsigned short Kl[2][64][64];      // 16 KB  K chunk dbuf (swizzled)
    __shared__ unsigned short Vl[2][64][64];      // 16 KB  V chunk dbuf (swizzled)

    int tid = threadIdx.x;
    int w = tid >> 6, lane = tid & 63;
    int fr = lane & 15, fg = lane >> 4;

    // XCD-colocation: all 8 qt-blocks of one (b,h) share an XCD.
    int lin = blockIdx.x;
    int xcd = lin & 7, jj = lin >> 3;          // jj in [0,64)
    int pair = xcd * 8 + (jj >> 3);            // 0..63 == h*4 + b
    int qt = jj & 7;
    int b = pair & 3, h = pair >> 2;

    int q0A = qt * 128 + w * 32;
    int q0B = q0A + 16;
    int swz = (fr & 7) << 2;                   // XOR on 4-byte-word index (P tile)
    int csw = fr & 7;                          // XOR on col16 index (K/V tiles)

    const unsigned short* Qp = Qh + ((size_t)(b * Hh + h)) * Lq * Dd;
    const unsigned short* Kp = Kh + ((size_t)(b * Hh + h)) * Lq * Dd;
    const unsigned short* Vp = Vt + ((size_t)(b * Hh + h)) * Dd * Lq;

    int srl = lane >> 3;                       // 0..7
    int scb = (lane & 7) ^ srl;                // pre-swizzled col16

#define STAGEK(BUF, KC) do {                                                     \
    _Pragma("unroll")                                                            \
    for (int i = 0; i < 2; ++i)                                                  \
        GLOAD_LDS16(Kp + (size_t)((KC) + w * 16 + i * 8 + srl) * Dd + scb * 8,   \
                    &Kl[BUF][w * 16 + i * 8][0]);                                \
} while (0)
#define STAGEV(BUF, KC) do {                                                     \
    _Pragma("unroll")                                                            \
    for (int i = 0; i < 2; ++i)                                                  \
        GLOAD_LDS16(Vp + (size_t)(w * 16 + i * 8 + srl) * Lq + (KC) + scb * 8,   \
                    &Vl[BUF][w * 16 + i * 8][0]);                                \
} while (0)

    for (int i = tid; i < 1024; i += 256) sBias[i] = mbias[b * Lq + i];

    bf16x8 qA0 = *(const bf16x8*)(Qp + (size_t)(q0A + fr) * Dd + fg * 8);
    bf16x8 qA1 = *(const bf16x8*)(Qp + (size_t)(q0A + fr) * Dd + 32 + fg * 8);
    bf16x8 qB0 = *(const bf16x8*)(Qp + (size_t)(q0B + fr) * Dd + fg * 8);
    bf16x8 qB1 = *(const bf16x8*)(Qp + (size_t)(q0B + fr) * Dd + 32 + fg * 8);

    f32x4 OA[4], OB[4];
#pragma unroll
    for (int dt = 0; dt < 4; ++dt) { OA[dt] = (f32x4){0.f,0.f,0.f,0.f}; OB[dt] = (f32x4){0.f,0.f,0.f,0.f}; }
    float mA = -INFINITY, lsA = 0.f, mB = -INFINITY, lsB = 0.f;

    bf16x8 vb0[4], vb1[4];

#define RDK(K0, K1, BUF) do {                                                    \
    _Pragma("unroll")                                                            \
    for (int kt = 0; kt < 4; ++kt) {                                             \
        K0[kt] = *(const bf16x8*)&Kl[BUF][kt * 16 + fr][(fg ^ csw) * 8];         \
        K1[kt] = *(const bf16x8*)&Kl[BUF][kt * 16 + fr][((4 + fg) ^ csw) * 8];   \
    }                                                                            \
} while (0)
#define RDV(BUF) do {                                                            \
    _Pragma("unroll")                                                            \
    for (int dt = 0; dt < 4; ++dt) {                                             \
        vb0[dt] = *(const bf16x8*)&Vl[BUF][dt * 16 + fr][(fg ^ csw) * 8];        \
        vb1[dt] = *(const bf16x8*)&Vl[BUF][dt * 16 + fr][((4 + fg) ^ csw) * 8];  \
    }                                                                            \
} while (0)

// QK with bias-initialized accumulator (BB[kt] = bias float4 for this k-range).
#define QK(S, K0, K1, B0, B1, BB) do {                                           \
    _Pragma("unroll")                                                            \
    for (int kt = 0; kt < 4; ++kt) {                                             \
        S[kt] = __builtin_amdgcn_mfma_f32_16x16x32_bf16(K0[kt], B0, BB[kt], 0, 0, 0); \
        S[kt] = __builtin_amdgcn_mfma_f32_16x16x32_bf16(K1[kt], B1, S[kt], 0, 0, 0); \
    }                                                                            \
} while (0)

// softmax + PV for one tile: S already holds (q.k)/8 + bias.
#define SMPV(S, MT, LS, OT, TI) do {                                             \
    float v_[16];                                                                \
    _Pragma("unroll")                                                            \
    for (int kt = 0; kt < 4; ++kt)                                               \
        _Pragma("unroll")                                                        \
        for (int r = 0; r < 4; ++r) v_[kt * 4 + r] = S[kt][r];                   \
    float t8[8];                                                                 \
    _Pragma("unroll")                                                            \
    for (int i = 0; i < 8; ++i) t8[i] = fmaxf(v_[i], v_[i + 8]);                 \
    float t4[4];                                                                 \
    _Pragma("unroll")                                                            \
    for (int i = 0; i < 4; ++i) t4[i] = fmaxf(t8[i], t8[i + 4]);                 \
    float pmax = fmaxf(fmaxf(t4[0], t4[1]), fmaxf(t4[2], t4[3]));                \
    pmax = cross_max(pmax);                                                      \
    float mn = fmaxf(MT, pmax);                                                  \
    float sc = __expf(MT - mn);                                                  \
    _Pragma("unroll")                                                            \
    for (int i = 0; i < 16; ++i) v_[i] = __expf(v_[i] - mn);                     \
    _Pragma("unroll")                                                            \
    for (int i = 0; i < 8; ++i) t8[i] = v_[i] + v_[i + 8];                       \
    _Pragma("unroll")                                                            \
    for (int i = 0; i < 4; ++i) t4[i] = t8[i] + t8[i + 4];                       \
    LS = LS * sc + (t4[0] + t4[1]) + (t4[2] + t4[3]);                            \
    MT = mn;                                                                     \
    _Pragma("unroll")                                                            \
    for (int dt = 0; dt < 4; ++dt)                                               \
        _Pragma("unroll")                                                        \
        for (int r = 0; r < 4; ++r) OT[dt][r] *= sc;                             \
    _Pragma("unroll")                                                            \
    for (int kt = 0; kt < 4; ++kt) {                                             \
        unsigned w0 = pack2(v_[kt * 4 + 0], v_[kt * 4 + 1]);                     \
        unsigned w1 = pack2(v_[kt * 4 + 2], v_[kt * 4 + 3]);                     \
        uint2 pr; pr.x = w0; pr.y = w1;                                          \
        *(uint2*)&Wl[w][TI][fr][2 * ((kt * 8 + fg * 2) ^ swz)] = pr;             \
    }                                                                            \
    bf16x8 pa0 = *(const bf16x8*)&Wl[w][TI][fr][2 * ((fg * 4) ^ swz)];           \
    bf16x8 pa1 = *(const bf16x8*)&Wl[w][TI][fr][2 * ((16 + fg * 4) ^ swz)];      \
    __builtin_amdgcn_s_setprio(1);                                               \
    _Pragma("unroll")                                                            \
    for (int dt = 0; dt < 4; ++dt) {                                             \
        OT[dt] = __builtin_amdgcn_mfma_f32_16x16x32_bf16(vb0[dt], pa0, OT[dt], 0, 0, 0); \
        OT[dt] = __builtin_amdgcn_mfma_f32_16x16x32_bf16(vb1[dt], pa1, OT[dt], 0, 0, 0); \
    }                                                                            \
    __builtin_amdgcn_s_setprio(0);                                               \
} while (0)

    // prologue: stage chunk 0 into buf 0 (drained by the barrier)
    STAGEK(0, 0);
    STAGEV(0, 0);
    __syncthreads();

#pragma unroll 1
    for (int c = 0; c < 16; ++c) {
        int cur = c & 1;
        if (c < 15) {                           // stage chunk c+1 into the other buf
            STAGEK(cur ^ 1, (c + 1) * 64);
            STAGEV(cur ^ 1, (c + 1) * 64);
        }
        bf16x8 k0[4], k1[4];
        RDK(k0, k1, cur);
        f32x4 bb[4];
#pragma unroll
        for (int kt = 0; kt < 4; ++kt)
            bb[kt] = *(const f32x4*)&sBias[c * 64 + kt * 16 + fg * 4];
        f32x4 SA[4], SB[4];
        __builtin_amdgcn_s_setprio(1);
        QK(SA, k0, k1, qA0, qA1, bb);
        QK(SB, k0, k1, qB0, qB1, bb);
        __builtin_amdgcn_s_setprio(0);
        RDV(cur);
        SMPV(SA, mA, lsA, OA, 0);
        SMPV(SB, mB, lsB, OB, 1);
        __syncthreads();                        // drains staging + guards dbuf
    }
#undef STAGEK
#undef STAGEV
#undef RDK
#undef RDV
#undef QK
#undef SMPV

    float lAt = cross_sum(lsA), lBt = cross_sum(lsB);
    float liA = 1.f / lAt, liB = 1.f / lBt;
#pragma unroll
    for (int dt = 0; dt < 4; ++dt) {
#pragma unroll
        for (int r = 0; r < 4; ++r) { OA[dt][r] *= liA; OB[dt][r] *= liB; }
    }
    // O^T layout: lane holds q = fr, d = dt*16 + fg*4 + r  (4 consecutive d)
#pragma unroll
    for (int dt = 0; dt < 4; ++dt) {
        uint2 pa; pa.x = pack2(OA[dt][0], OA[dt][1]); pa.y = pack2(OA[dt][2], OA[dt][3]);
        *(uint2*)(ctx + ((size_t)(b * Lq + q0A + fr)) * Emb + h * Dd + dt * 16 + fg * 4) = pa;
        uint2 pb; pb.x = pack2(OB[dt][0], OB[dt][1]); pb.y = pack2(OB[dt][2], OB[dt][3]);
        *(uint2*)(ctx + ((size_t)(b * Lq + q0B + fr)) * Emb + h * Dd + dt * 16 + fg * 4) = pb;
    }

    if (lane < 16) {
        mstats[(size_t)(b * Hh + h) * Lq + q0A + lane] = mA;
        lstats[(size_t)(b * Hh + h) * Lq + q0A + lane] = liA;
        mstats[(size_t)(b * Hh + h) * Lq + q0B + lane] = mB;
        lstats[(size_t)(b * Hh + h) * Lq + q0B + lane] = liB;
    }
}

// ---------------------------------------------------------------------------
// Tail: gemm_o and attn_out2 fused (r19 interleave, r20 bias-in-accumulator).
// ---------------------------------------------------------------------------
__global__ __launch_bounds__(256) void tail_fused(const unsigned short* __restrict__ A,
                                                  const unsigned short* __restrict__ Bw,
                                                  const float* __restrict__ bias,
                                                  float* __restrict__ outp,
                                                  const unsigned short* __restrict__ Qh,
                                                  const unsigned short* __restrict__ Kh,
                                                  const float* __restrict__ mbias,
                                                  const float* __restrict__ mstats,
                                                  const float* __restrict__ lstats,
                                                  float* __restrict__ out2)
{
    __shared__ char smem[49152];
    const int K = 1024;
    int tid = threadIdx.x;
    int w = tid >> 6, lane = tid & 63;
    int fr = lane & 15, fg = lane >> 4;
    int csw = fr & 7;
    int srl = lane >> 3;
    int scb = (lane & 7) ^ srl;

    int role_gemm, rid;
    if (blockIdx.x < 1024) { role_gemm = !(blockIdx.x & 1); rid = blockIdx.x >> 1; }
    else                   { role_gemm = 0; rid = 512 + (blockIdx.x - 1024); }

    if (role_gemm) {
        // ------------------- gemm_o role (rid in [0,512)) -------------------
        unsigned short (*sA)[64][64]  = (unsigned short(*)[64][64])smem;            // 16 KB
        unsigned short (*sB)[128][64] = (unsigned short(*)[128][64])(smem + 16384); // 32 KB

        int lin = rid;
        int xcd = lin & 7, idx = lin >> 3;
        int bm = (xcd * 8 + (idx >> 3)) * 64;
        int bn = (idx & 7) * 128;
        int wr = (w >> 1) * 32, wc = (w & 1) * 64;

        const unsigned short* Ag = A + (size_t)(bm + w * 16 + srl) * K + scb * 8;
        const unsigned short* Bg = Bw + (size_t)(bn + w * 32 + srl) * K + scb * 8;

#define STAGE_O(BUF, K0) do {                                                    \
    _Pragma("unroll")                                                            \
    for (int j = 0; j < 2; ++j)                                                  \
        GLOAD_LDS16(Ag + (size_t)j * 8 * K + (K0), &sA[BUF][w * 16 + j * 8][0]); \
    _Pragma("unroll")                                                            \
    for (int j = 0; j < 4; ++j)                                                  \
        GLOAD_LDS16(Bg + (size_t)j * 8 * K + (K0), &sB[BUF][w * 32 + j * 8][0]); \
} while (0)

        f32x4 acc[2][4];
#pragma unroll
        for (int i = 0; i < 2; ++i)
#pragma unroll
            for (int j = 0; j < 4; ++j) acc[i][j] = (f32x4){0.f, 0.f, 0.f, 0.f};

        STAGE_O(0, 0);
        __syncthreads();

#pragma unroll 1
        for (int k0 = 0; k0 < K; k0 += 64) {
            int cur = (k0 >> 6) & 1;
            if (k0 + 64 < K) STAGE_O(cur ^ 1, k0 + 64);
            bf16x8 af[2][2], bfv[4][2];
#pragma unroll
            for (int i = 0; i < 2; ++i)
#pragma unroll
                for (int kk = 0; kk < 2; ++kk)
                    af[i][kk] = *(const bf16x8*)&sA[cur][wr + i * 16 + fr][((kk * 4 + fg) ^ csw) * 8];
#pragma unroll
            for (int j = 0; j < 4; ++j)
#pragma unroll
                for (int kk = 0; kk < 2; ++kk)
                    bfv[j][kk] = *(const bf16x8*)&sB[cur][wc + j * 16 + fr][((kk * 4 + fg) ^ csw) * 8];
#pragma unroll
            for (int i = 0; i < 2; ++i)
#pragma unroll
                for (int j = 0; j < 4; ++j) {
                    acc[i][j] = __builtin_amdgcn_mfma_f32_16x16x32_bf16(af[i][0], bfv[j][0], acc[i][j], 0, 0, 0);
                    acc[i][j] = __builtin_amdgcn_mfma_f32_16x16x32_bf16(af[i][1], bfv[j][1], acc[i][j], 0, 0, 0);
                }
            __syncthreads();
        }
#undef STAGE_O

        int rb = (lane >> 4) * 4;
#pragma unroll
        for (int j = 0; j < 4; ++j) {
            int n = bn + wc + j * 16 + fr;
            float bia = bias[n];
#pragma unroll
            for (int i = 0; i < 2; ++i)
#pragma unroll
                for (int r = 0; r < 4; ++r) {
                    int m = bm + wr + i * 16 + rb + r;
                    outp[(size_t)m * 1024 + n] = acc[i][j][r] + bia;
                }
        }
    } else {
        // ------------------- attn_out2 role (rid in [0,1024)) ----------------
        unsigned short (*sQ)[32][64]  = (unsigned short(*)[32][64])smem;            // 8 KB
        unsigned short (*sK)[128][64] = (unsigned short(*)[128][64])(smem + 8192);  // 32 KB
        float (*sM)[32]  = (float(*)[32])(smem + 40960);                            // 2 KB
        float (*sLi)[32] = (float(*)[32])(smem + 43008);                            // 2 KB

        int q0 = (rid & 31) * 32;
        int kc = ((rid >> 5) & 7) * 128;
        int b  = rid >> 8;

        for (int i = tid; i < 512; i += 256) {
            int h = i >> 5, qq = i & 31;
            sM[h][qq]  = mstats[(size_t)(b * Hh + h) * Lq + q0 + qq];
            sLi[h][qq] = lstats[(size_t)(b * Hh + h) * Lq + q0 + qq];
        }

#define STAGEH(BUF, H) do {                                                      \
    const unsigned short* Qp_ = Qh + ((size_t)(b * Hh + (H))) * Lq * Dd;         \
    const unsigned short* Kp_ = Kh + ((size_t)(b * Hh + (H))) * Lq * Dd;         \
    GLOAD_LDS16(Qp_ + (size_t)(q0 + w * 8 + srl) * Dd + scb * 8, &sQ[BUF][w * 8][0]); \
    _Pragma("unroll")                                                            \
    for (int i = 0; i < 4; ++i)                                                  \
        GLOAD_LDS16(Kp_ + (size_t)(kc + w * 32 + i * 8 + srl) * Dd + scb * 8,    \
                    &sK[BUF][w * 32 + i * 8][0]);                                \
} while (0)

#define RDH(AQ, BKk, BUF) do {                                                   \
    _Pragma("unroll")                                                            \
    for (int rt = 0; rt < 2; ++rt)                                               \
        _Pragma("unroll")                                                        \
        for (int ks = 0; ks < 2; ++ks)                                           \
            AQ[rt][ks] = *(const bf16x8*)&sQ[BUF][rt * 16 + fr][((ks * 4 + fg) ^ csw) * 8]; \
    _Pragma("unroll")                                                            \
    for (int ct = 0; ct < 2; ++ct)                                               \
        _Pragma("unroll")                                                        \
        for (int ks = 0; ks < 2; ++ks)                                           \
            BKk[ct][ks] = *(const bf16x8*)&sK[BUF][w * 32 + ct * 16 + fr][((ks * 4 + fg) ^ csw) * 8]; \
} while (0)

#define COMPH(AQ, BKk, H) do {                                                   \
    float4 mrow[2], lirow[2];                                                    \
    _Pragma("unroll")                                                            \
    for (int rt = 0; rt < 2; ++rt) {                                             \
        mrow[rt]  = *(const float4*)&sM[(H)][rt * 16 + fg * 4];                  \
        lirow[rt] = *(const float4*)&sLi[(H)][rt * 16 + fg * 4];                 \
    }                                                                            \
    _Pragma("unroll")                                                            \
    for (int rt = 0; rt < 2; ++rt)                                               \
        _Pragma("unroll")                                                        \
        for (int ct = 0; ct < 2; ++ct) {                                         \
            f32x4 binit = ct ? (f32x4){bias1,bias1,bias1,bias1}                  \
                             : (f32x4){bias0,bias0,bias0,bias0};                 \
            f32x4 s_ = __builtin_amdgcn_mfma_f32_16x16x32_bf16(AQ[rt][0], BKk[ct][0], binit, 0, 0, 0); \
            s_ = __builtin_amdgcn_mfma_f32_16x16x32_bf16(AQ[rt][1], BKk[ct][1], s_, 0, 0, 0); \
            _Pragma("unroll")                                                    \
            for (int r = 0; r < 4; ++r)                                          \
                o2[rt][ct][r] += __expf(s_[r] - mrow[rt][r]) * lirow[rt][r];     \
        }                                                                        \
} while (0)

        float bias0 = mbias[b * Lq + kc + w * 32 + fr];
        float bias1 = mbias[b * Lq + kc + w * 32 + 16 + fr];

        float o2[2][2][4];
#pragma unroll
        for (int rt = 0; rt < 2; ++rt)
#pragma unroll
            for (int ct = 0; ct < 2; ++ct)
#pragma unroll
                for (int r = 0; r < 4; ++r) o2[rt][ct][r] = 0.f;

        STAGEH(0, 0);
        __syncthreads();

#pragma unroll 1
        for (int h = 0; h < Hh; ++h) {
            int cur = h & 1;
            if (h < Hh - 1) STAGEH(cur ^ 1, h + 1);
            bf16x8 aq[2][2], bk[2][2];
            RDH(aq, bk, cur);
            COMPH(aq, bk, h);
            __syncthreads();
        }
#undef STAGEH
#undef RDH
#undef COMPH

#pragma unroll
        for (int rt = 0; rt < 2; ++rt)
#pragma unroll
            for (int ct = 0; ct < 2; ++ct)
#pragma unroll
                for (int r = 0; r < 4; ++r)
                    out2[((size_t)(b * Lq + q0 + rt * 16 + fg * 4 + r)) * Lq + kc + w * 32 + ct * 16 + fr]
                        = o2[rt][ct][r] * 0.0625f;
    }
}

// ---------------------------------------------------------------------------
extern "C" void kernel_launch(void* const* d_in, const int* in_sizes, int n_in,
                              void* d_out, int out_size, void* d_ws, size_t ws_size,
                              hipStream_t stream)
{
    const float* query = (const float*)d_in[0];
    const float* key   = (const float*)d_in[1];
    const float* value = (const float*)d_in[2];
    const float* amask = (const float*)d_in[3];
    const int*   kpm   = (const int*)d_in[4];
    const float* Wq = (const float*)d_in[5];
    const float* bq = (const float*)d_in[6];
    const float* Wk = (const float*)d_in[7];
    const float* bk = (const float*)d_in[8];
    const float* Wv = (const float*)d_in[9];
    const float* bv = (const float*)d_in[10];
    const float* Wo = (const float*)d_in[11];
    const float* bo = (const float*)d_in[12];

    float* out1 = (float*)d_out;                       // (B,L,E) f32
    float* out2 = out1 + (size_t)Bsz * Lq * Emb;       // (B,L,L) f32

    const size_t MB = 1u << 20;
    char* ws = (char*)d_ws;
    unsigned short* qbf = (unsigned short*)(ws + 0 * MB);
    unsigned short* kbf = (unsigned short*)(ws + 8 * MB);
    unsigned short* vbf = (unsigned short*)(ws + 16 * MB);
    unsigned short* wqb = (unsigned short*)(ws + 24 * MB);
    unsigned short* wkb = (unsigned short*)(ws + 26 * MB);
    unsigned short* wvb = (unsigned short*)(ws + 28 * MB);
    unsigned short* wob = (unsigned short*)(ws + 30 * MB);
    unsigned short* QhB = (unsigned short*)(ws + 32 * MB);  // (B,H,L,D) bf16 (pre-scaled x0.125)
    unsigned short* KhB = (unsigned short*)(ws + 40 * MB);
    unsigned short* VtB = (unsigned short*)(ws + 48 * MB);  // (B,H,D,L) bf16
    unsigned short* ctxB = (unsigned short*)(ws + 56 * MB); // (B,L,E) bf16
    float* mbias  = (float*)(ws + 64 * MB);                 // 16 KB
    // stats alias the qbf region (dead after gemm_qkv)
    float* mstats = (float*)(ws + 0 * MB);                  // 256 KB
    float* lstats = (float*)(ws + 0 * MB + 256 * 1024);     // 256 KB

    cvt_all<<<16400, 256, 0, stream>>>(query, key, value, Wq, Wk, Wv, Wo,
                                       qbf, kbf, vbf, wqb, wkb, wvb, wob,
                                       amask, kpm, mbias);

    gemm_qkv<<<768, 256, 0, stream>>>(qbf, kbf, vbf, wqb, wkb, wvb,
                                      bq, bk, bv, QhB, KhB, VtB);

    attn_flash<<<512, 256, 0, stream>>>(QhB, KhB, VtB, mbias, ctxB, mstats, lstats);

    tail_fused<<<1536, 256, 0, stream>>>(ctxB, wob, bo, out1,
                                         QhB, KhB, mbias, mstats, lstats, out2);
}

// Round 23
// 139.237 us; speedup vs baseline: 1.0071x; 1.0071x over previous
//
#include <hip/hip_runtime.h>
#include <math.h>

#define Bsz 4
#define Lq  1024
#define Emb 1024
#define Hh  16
#define Dd  64

typedef short bf16x8 __attribute__((ext_vector_type(8)));
typedef float f32x4 __attribute__((ext_vector_type(4)));

static __device__ __forceinline__ unsigned short f2bf(float f) {
    unsigned u = __float_as_uint(f);
    return (unsigned short)((u + 0x7FFFu + ((u >> 16) & 1u)) >> 16);
}
// pack two f32 -> two bf16 (round-half-up) in one v_perm
static __device__ __forceinline__ unsigned pack2(float lo, float hi) {
    return __builtin_amdgcn_perm(__float_as_uint(hi) + 0x8000u,
                                 __float_as_uint(lo) + 0x8000u, 0x07060302u);
}

// cross-fg reduces (lanes {l, l^16, l^32, l^48}); proven-correct shfl form.
static __device__ __forceinline__ float cross_max(float x) {
    x = fmaxf(x, __shfl_xor(x, 16, 64));
    x = fmaxf(x, __shfl_xor(x, 32, 64));
    return x;
}
static __device__ __forceinline__ float cross_sum(float x) {
    x += __shfl_xor(x, 16, 64);
    x += __shfl_xor(x, 32, 64);
    return x;
}

// global -> LDS direct copy, 16 B per lane.
#define GLOAD_LDS16(gp, lp) __builtin_amdgcn_global_load_lds(                  \
    (const __attribute__((address_space(1))) void*)(gp),                       \
    (__attribute__((address_space(3))) void*)(lp), 16, 0, 0)

// ---------------------------------------------------------------------------
// One launch: converts q,k,v (3 x 1048576 float4) + 4 weights (4 x 262144)
// and computes the mask bias (blocks >= 16384).
__global__ __launch_bounds__(256) void cvt_all(const float* __restrict__ q,
                                               const float* __restrict__ k,
                                               const float* __restrict__ v,
                                               const float* __restrict__ w0,
                                               const float* __restrict__ w1,
                                               const float* __restrict__ w2,
                                               const float* __restrict__ w3,
                                               unsigned short* __restrict__ qo,
                                               unsigned short* __restrict__ ko,
                                               unsigned short* __restrict__ vo,
                                               unsigned short* __restrict__ o0,
                                               unsigned short* __restrict__ o1,
                                               unsigned short* __restrict__ o2,
                                               unsigned short* __restrict__ o3,
                                               const float* __restrict__ mask,
                                               const int* __restrict__ kpm,
                                               float* __restrict__ bias)
{
    if (blockIdx.x >= 16384) {
        int i = (blockIdx.x - 16384) * 256 + threadIdx.x;   // 0..4095
        float bv = 8.0f * logf(fmaxf(mask[i], 1e-6f));
        bias[i] = kpm[i] ? -INFINITY : bv;
        return;
    }
    int i = blockIdx.x * 256 + threadIdx.x;
    const float* src; unsigned short* dst; int off;
    if (i < 1048576)      { src = q; dst = qo; off = i; }
    else if (i < 2097152) { src = k; dst = ko; off = i - 1048576; }
    else if (i < 3145728) { src = v; dst = vo; off = i - 2097152; }
    else {
        int j = i - 3145728;
        int reg = j >> 18; off = j & 262143;
        src = (reg == 0) ? w0 : (reg == 1) ? w1 : (reg == 2) ? w2 : w3;
        dst = (reg == 0) ? o0 : (reg == 1) ? o1 : (reg == 2) ? o2 : o3;
    }
    float4 x = ((const float4*)src)[off];
    ushort4 o;
    o.x = f2bf(x.x); o.y = f2bf(x.y); o.z = f2bf(x.z); o.w = f2bf(x.w);
    ((ushort4*)dst)[off] = o;
}

// ---------------------------------------------------------------------------
// Fused Q/K/V projections, stage-ahead dbuf structure (r12-validated,
// 64x128 tile, grid 1536).  Q output (which==0) is PRE-SCALED by 0.125.
// ---------------------------------------------------------------------------
__global__ __launch_bounds__(256) void gemm_qkv(const unsigned short* __restrict__ Aq,
                                                const unsigned short* __restrict__ Ak,
                                                const unsigned short* __restrict__ Av,
                                                const unsigned short* __restrict__ Wq,
                                                const unsigned short* __restrict__ Wk,
                                                const unsigned short* __restrict__ Wv,
                                                const float* __restrict__ biq,
                                                const float* __restrict__ bik,
                                                const float* __restrict__ biv,
                                                unsigned short* __restrict__ Oq,
                                                unsigned short* __restrict__ Ok,
                                                unsigned short* __restrict__ Ov)
{
    const int K = 1024;
    __shared__ unsigned short sA[2][64][64];    // 16 KB  dbuf, swizzled
    __shared__ unsigned short sB[2][128][64];   // 32 KB  dbuf, swizzled
    int tid = threadIdx.x;
    int w = tid >> 6, lane = tid & 63;

    int bid = blockIdx.x;
    int which = bid >> 9;              // 0=Q 1=K 2=V
    int lin = bid & 511;
    int xcd = lin & 7, idx = lin >> 3; // idx in [0,64)
    int bm = (xcd * 8 + (idx >> 3)) * 64;
    int bn = (idx & 7) * 128;

    const unsigned short* A = (which == 0) ? Aq : (which == 1) ? Ak : Av;
    const unsigned short* Bw = (which == 0) ? Wq : (which == 1) ? Wk : Wv;
    const float* bias = (which == 0) ? biq : (which == 1) ? bik : biv;
    unsigned short* outp = (which == 0) ? Oq : (which == 1) ? Ok : Ov;

    int wr = (w >> 1) * 32, wc = (w & 1) * 64;
    int fr = lane & 15, fg = lane >> 4;
    int csw = fr & 7;                  // read-side XOR on col16 unit

    int srl = lane >> 3;               // 0..7
    int scb = (lane & 7) ^ srl;        // pre-swizzled col16 on stage

    const unsigned short* Ag = A + (size_t)(bm + w * 16 + srl) * K + scb * 8;
    const unsigned short* Bg = Bw + (size_t)(bn + w * 32 + srl) * K + scb * 8;

#define STAGE(BUF, K0) do {                                                      \
    _Pragma("unroll")                                                            \
    for (int j = 0; j < 2; ++j)                                                  \
        GLOAD_LDS16(Ag + (size_t)j * 8 * K + (K0), &sA[BUF][w * 16 + j * 8][0]); \
    _Pragma("unroll")                                                            \
    for (int j = 0; j < 4; ++j)                                                  \
        GLOAD_LDS16(Bg + (size_t)j * 8 * K + (K0), &sB[BUF][w * 32 + j * 8][0]); \
} while (0)

    f32x4 acc[2][4];
#pragma unroll
    for (int i = 0; i < 2; ++i)
#pragma unroll
        for (int j = 0; j < 4; ++j) acc[i][j] = (f32x4){0.f, 0.f, 0.f, 0.f};

    STAGE(0, 0);
    __syncthreads();

#pragma unroll 1
    for (int k0 = 0; k0 < K; k0 += 64) {
        int cur = (k0 >> 6) & 1;
        if (k0 + 64 < K) STAGE(cur ^ 1, k0 + 64);
        bf16x8 af[2][2], bfv[4][2];
#pragma unroll
        for (int i = 0; i < 2; ++i)
#pragma unroll
            for (int kk = 0; kk < 2; ++kk)
                af[i][kk] = *(const bf16x8*)&sA[cur][wr + i * 16 + fr][((kk * 4 + fg) ^ csw) * 8];
#pragma unroll
        for (int j = 0; j < 4; ++j)
#pragma unroll
            for (int kk = 0; kk < 2; ++kk)
                bfv[j][kk] = *(const bf16x8*)&sB[cur][wc + j * 16 + fr][((kk * 4 + fg) ^ csw) * 8];
#pragma unroll
        for (int i = 0; i < 2; ++i)
#pragma unroll
            for (int j = 0; j < 4; ++j) {
                acc[i][j] = __builtin_amdgcn_mfma_f32_16x16x32_bf16(af[i][0], bfv[j][0], acc[i][j], 0, 0, 0);
                acc[i][j] = __builtin_amdgcn_mfma_f32_16x16x32_bf16(af[i][1], bfv[j][1], acc[i][j], 0, 0, 0);
            }
        __syncthreads();
    }
#undef STAGE

    int rb = (lane >> 4) * 4;
    float osc = (which == 0) ? 0.125f : 1.0f;   // fold QK^T scale into Q
#pragma unroll
    for (int j = 0; j < 4; ++j) {
        int n = bn + wc + j * 16 + fr;
        float bia = bias[n];
#pragma unroll
        for (int i = 0; i < 2; ++i) {
#pragma unroll
            for (int r = 0; r < 4; ++r) {
                int m = bm + wr + i * 16 + rb + r;
                float v = (acc[i][j][r] + bia) * osc;
                int b = m >> 10, l = m & 1023, h = n >> 6, d = n & 63;
                if (which == 2)
                    outp[(((size_t)(b * Hh + h)) * Dd + d) * Lq + l] = f2bf(v);
                else
                    outp[(((size_t)(b * Hh + h)) * Lq + l) * Dd + d] = f2bf(v);
            }
        }
    }
}

// ---------------------------------------------------------------------------
// Pass C: flash attention (r20-validated: bias-in-accumulator, pre-scaled Q,
// setprio around MFMA clusters, deferred l).
// ---------------------------------------------------------------------------
__global__ __launch_bounds__(256) void attn_flash(const unsigned short* __restrict__ Qh,
                                                  const unsigned short* __restrict__ Kh,
                                                  const unsigned short* __restrict__ Vt,
                                                  const float* __restrict__ mbias,
                                                  unsigned short* __restrict__ ctx,
                                                  float* __restrict__ mstats,
                                                  float* __restrict__ lstats)
{
    __shared__ float sBias[1024];                 // 4 KB
    __shared__ unsigned short Wl[4][2][16][64];   // 16 KB  per-wave P tiles
    __shared__ unsigned short Kl[2][64][64];      // 16 KB  K chunk dbuf (swizzled)
    __shared__ unsigned short Vl[2][64][64];      // 16 KB  V chunk dbuf (swizzled)

    int tid = threadIdx.x;
    int w = tid >> 6, lane = tid & 63;
    int fr = lane & 15, fg = lane >> 4;

    // XCD-colocation: all 8 qt-blocks of one (b,h) share an XCD.
    int lin = blockIdx.x;
    int xcd = lin & 7, jj = lin >> 3;          // jj in [0,64)
    int pair = xcd * 8 + (jj >> 3);            // 0..63 == h*4 + b
    int qt = jj & 7;
    int b = pair & 3, h = pair >> 2;

    int q0A = qt * 128 + w * 32;
    int q0B = q0A + 16;
    int swz = (fr & 7) << 2;                   // XOR on 4-byte-word index (P tile)
    int csw = fr & 7;                          // XOR on col16 index (K/V tiles)

    const unsigned short* Qp = Qh + ((size_t)(b * Hh + h)) * Lq * Dd;
    const unsigned short* Kp = Kh + ((size_t)(b * Hh + h)) * Lq * Dd;
    const unsigned short* Vp = Vt + ((size_t)(b * Hh + h)) * Dd * Lq;

    int srl = lane >> 3;                       // 0..7
    int scb = (lane & 7) ^ srl;                // pre-swizzled col16

#define STAGEK(BUF, KC) do {                                                     \
    _Pragma("unroll")                                                            \
    for (int i = 0; i < 2; ++i)                                                  \
        GLOAD_LDS16(Kp + (size_t)((KC) + w * 16 + i * 8 + srl) * Dd + scb * 8,   \
                    &Kl[BUF][w * 16 + i * 8][0]);                                \
} while (0)
#define STAGEV(BUF, KC) do {                                                     \
    _Pragma("unroll")                                                            \
    for (int i = 0; i < 2; ++i)                                                  \
        GLOAD_LDS16(Vp + (size_t)(w * 16 + i * 8 + srl) * Lq + (KC) + scb * 8,   \
                    &Vl[BUF][w * 16 + i * 8][0]);                                \
} while (0)

    for (int i = tid; i < 1024; i += 256) sBias[i] = mbias[b * Lq + i];

    bf16x8 qA0 = *(const bf16x8*)(Qp + (size_t)(q0A + fr) * Dd + fg * 8);
    bf16x8 qA1 = *(const bf16x8*)(Qp + (size_t)(q0A + fr) * Dd + 32 + fg * 8);
    bf16x8 qB0 = *(const bf16x8*)(Qp + (size_t)(q0B + fr) * Dd + fg * 8);
    bf16x8 qB1 = *(const bf16x8*)(Qp + (size_t)(q0B + fr) * Dd + 32 + fg * 8);

    f32x4 OA[4], OB[4];
#pragma unroll
    for (int dt = 0; dt < 4; ++dt) { OA[dt] = (f32x4){0.f,0.f,0.f,0.f}; OB[dt] = (f32x4){0.f,0.f,0.f,0.f}; }
    float mA = -INFINITY, lsA = 0.f, mB = -INFINITY, lsB = 0.f;

    bf16x8 vb0[4], vb1[4];

#define RDK(K0, K1, BUF) do {                                                    \
    _Pragma("unroll")                                                            \
    for (int kt = 0; kt < 4; ++kt) {                                             \
        K0[kt] = *(const bf16x8*)&Kl[BUF][kt * 16 + fr][(fg ^ csw) * 8];         \
        K1[kt] = *(const bf16x8*)&Kl[BUF][kt * 16 + fr][((4 + fg) ^ csw) * 8];   \
    }                                                                            \
} while (0)
#define RDV(BUF) do {                                                            \
    _Pragma("unroll")                                                            \
    for (int dt = 0; dt < 4; ++dt) {                                             \
        vb0[dt] = *(const bf16x8*)&Vl[BUF][dt * 16 + fr][(fg ^ csw) * 8];        \
        vb1[dt] = *(const bf16x8*)&Vl[BUF][dt * 16 + fr][((4 + fg) ^ csw) * 8];  \
    }                                                                            \
} while (0)

// QK with bias-initialized accumulator (BB[kt] = bias float4 for this k-range).
#define QK(S, K0, K1, B0, B1, BB) do {                                           \
    _Pragma("unroll")                                                            \
    for (int kt = 0; kt < 4; ++kt) {                                             \
        S[kt] = __builtin_amdgcn_mfma_f32_16x16x32_bf16(K0[kt], B0, BB[kt], 0, 0, 0); \
        S[kt] = __builtin_amdgcn_mfma_f32_16x16x32_bf16(K1[kt], B1, S[kt], 0, 0, 0); \
    }                                                                            \
} while (0)

// softmax + PV for one tile: S already holds (q.k)/8 + bias.
#define SMPV(S, MT, LS, OT, TI) do {                                             \
    float v_[16];                                                                \
    _Pragma("unroll")                                                            \
    for (int kt = 0; kt < 4; ++kt)                                               \
        _Pragma("unroll")                                                        \
        for (int r = 0; r < 4; ++r) v_[kt * 4 + r] = S[kt][r];                   \
    float t8[8];                                                                 \
    _Pragma("unroll")                                                            \
    for (int i = 0; i < 8; ++i) t8[i] = fmaxf(v_[i], v_[i + 8]);                 \
    float t4[4];                                                                 \
    _Pragma("unroll")                                                            \
    for (int i = 0; i < 4; ++i) t4[i] = fmaxf(t8[i], t8[i + 4]);                 \
    float pmax = fmaxf(fmaxf(t4[0], t4[1]), fmaxf(t4[2], t4[3]));                \
    pmax = cross_max(pmax);                                                      \
    float mn = fmaxf(MT, pmax);                                                  \
    float sc = __expf(MT - mn);                                                  \
    _Pragma("unroll")                                                            \
    for (int i = 0; i < 16; ++i) v_[i] = __expf(v_[i] - mn);                     \
    _Pragma("unroll")                                                            \
    for (int i = 0; i < 8; ++i) t8[i] = v_[i] + v_[i + 8];                       \
    _Pragma("unroll")                                                            \
    for (int i = 0; i < 4; ++i) t4[i] = t8[i] + t8[i + 4];                       \
    LS = LS * sc + (t4[0] + t4[1]) + (t4[2] + t4[3]);                            \
    MT = mn;                                                                     \
    _Pragma("unroll")                                                            \
    for (int dt = 0; dt < 4; ++dt)                                               \
        _Pragma("unroll")                                                        \
        for (int r = 0; r < 4; ++r) OT[dt][r] *= sc;                             \
    _Pragma("unroll")                                                            \
    for (int kt = 0; kt < 4; ++kt) {                                             \
        unsigned w0 = pack2(v_[kt * 4 + 0], v_[kt * 4 + 1]);                     \
        unsigned w1 = pack2(v_[kt * 4 + 2], v_[kt * 4 + 3]);                     \
        uint2 pr; pr.x = w0; pr.y = w1;                                          \
        *(uint2*)&Wl[w][TI][fr][2 * ((kt * 8 + fg * 2) ^ swz)] = pr;             \
    }                                                                            \
    bf16x8 pa0 = *(const bf16x8*)&Wl[w][TI][fr][2 * ((fg * 4) ^ swz)];           \
    bf16x8 pa1 = *(const bf16x8*)&Wl[w][TI][fr][2 * ((16 + fg * 4) ^ swz)];      \
    __builtin_amdgcn_s_setprio(1);                                               \
    _Pragma("unroll")                                                            \
    for (int dt = 0; dt < 4; ++dt) {                                             \
        OT[dt] = __builtin_amdgcn_mfma_f32_16x16x32_bf16(vb0[dt], pa0, OT[dt], 0, 0, 0); \
        OT[dt] = __builtin_amdgcn_mfma_f32_16x16x32_bf16(vb1[dt], pa1, OT[dt], 0, 0, 0); \
    }                                                                            \
    __builtin_amdgcn_s_setprio(0);                                               \
} while (0)

    // prologue: stage chunk 0 into buf 0 (drained by the barrier)
    STAGEK(0, 0);
    STAGEV(0, 0);
    __syncthreads();

#pragma unroll 1
    for (int c = 0; c < 16; ++c) {
        int cur = c & 1;
        if (c < 15) {                           // stage chunk c+1 into the other buf
            STAGEK(cur ^ 1, (c + 1) * 64);
            STAGEV(cur ^ 1, (c + 1) * 64);
        }
        bf16x8 k0[4], k1[4];
        RDK(k0, k1, cur);
        f32x4 bb[4];
#pragma unroll
        for (int kt = 0; kt < 4; ++kt)
            bb[kt] = *(const f32x4*)&sBias[c * 64 + kt * 16 + fg * 4];
        f32x4 SA[4], SB[4];
        __builtin_amdgcn_s_setprio(1);
        QK(SA, k0, k1, qA0, qA1, bb);
        QK(SB, k0, k1, qB0, qB1, bb);
        __builtin_amdgcn_s_setprio(0);
        RDV(cur);
        SMPV(SA, mA, lsA, OA, 0);
        SMPV(SB, mB, lsB, OB, 1);
        __syncthreads();                        // drains staging + guards dbuf
    }
#undef STAGEK
#undef STAGEV
#undef RDK
#undef RDV
#undef QK
#undef SMPV

    float lAt = cross_sum(lsA), lBt = cross_sum(lsB);
    float liA = 1.f / lAt, liB = 1.f / lBt;
#pragma unroll
    for (int dt = 0; dt < 4; ++dt) {
#pragma unroll
        for (int r = 0; r < 4; ++r) { OA[dt][r] *= liA; OB[dt][r] *= liB; }
    }
    // O^T layout: lane holds q = fr, d = dt*16 + fg*4 + r  (4 consecutive d)
#pragma unroll
    for (int dt = 0; dt < 4; ++dt) {
        uint2 pa; pa.x = pack2(OA[dt][0], OA[dt][1]); pa.y = pack2(OA[dt][2], OA[dt][3]);
        *(uint2*)(ctx + ((size_t)(b * Lq + q0A + fr)) * Emb + h * Dd + dt * 16 + fg * 4) = pa;
        uint2 pb; pb.x = pack2(OB[dt][0], OB[dt][1]); pb.y = pack2(OB[dt][2], OB[dt][3]);
        *(uint2*)(ctx + ((size_t)(b * Lq + q0B + fr)) * Emb + h * Dd + dt * 16 + fg * 4) = pb;
    }

    if (lane < 16) {
        mstats[(size_t)(b * Hh + h) * Lq + q0A + lane] = mA;
        lstats[(size_t)(b * Hh + h) * Lq + q0A + lane] = liA;
        mstats[(size_t)(b * Hh + h) * Lq + q0B + lane] = mB;
        lstats[(size_t)(b * Hh + h) * Lq + q0B + lane] = liB;
    }
}

// ---------------------------------------------------------------------------
// Tail: gemm_o and attn_out2 fused (r19 interleave, r20 bias-in-accumulator).
// ---------------------------------------------------------------------------
__global__ __launch_bounds__(256) void tail_fused(const unsigned short* __restrict__ A,
                                                  const unsigned short* __restrict__ Bw,
                                                  const float* __restrict__ bias,
                                                  float* __restrict__ outp,
                                                  const unsigned short* __restrict__ Qh,
                                                  const unsigned short* __restrict__ Kh,
                                                  const float* __restrict__ mbias,
                                                  const float* __restrict__ mstats,
                                                  const float* __restrict__ lstats,
                                                  float* __restrict__ out2)
{
    __shared__ char smem[49152];
    const int K = 1024;
    int tid = threadIdx.x;
    int w = tid >> 6, lane = tid & 63;
    int fr = lane & 15, fg = lane >> 4;
    int csw = fr & 7;
    int srl = lane >> 3;
    int scb = (lane & 7) ^ srl;

    int role_gemm, rid;
    if (blockIdx.x < 1024) { role_gemm = !(blockIdx.x & 1); rid = blockIdx.x >> 1; }
    else                   { role_gemm = 0; rid = 512 + (blockIdx.x - 1024); }

    if (role_gemm) {
        // ------------------- gemm_o role (rid in [0,512)) -------------------
        unsigned short (*sA)[64][64]  = (unsigned short(*)[64][64])smem;            // 16 KB
        unsigned short (*sB)[128][64] = (unsigned short(*)[128][64])(smem + 16384); // 32 KB

        int lin = rid;
        int xcd = lin & 7, idx = lin >> 3;
        int bm = (xcd * 8 + (idx >> 3)) * 64;
        int bn = (idx & 7) * 128;
        int wr = (w >> 1) * 32, wc = (w & 1) * 64;

        const unsigned short* Ag = A + (size_t)(bm + w * 16 + srl) * K + scb * 8;
        const unsigned short* Bg = Bw + (size_t)(bn + w * 32 + srl) * K + scb * 8;

#define STAGE_O(BUF, K0) do {                                                    \
    _Pragma("unroll")                                                            \
    for (int j = 0; j < 2; ++j)                                                  \
        GLOAD_LDS16(Ag + (size_t)j * 8 * K + (K0), &sA[BUF][w * 16 + j * 8][0]); \
    _Pragma("unroll")                                                            \
    for (int j = 0; j < 4; ++j)                                                  \
        GLOAD_LDS16(Bg + (size_t)j * 8 * K + (K0), &sB[BUF][w * 32 + j * 8][0]); \
} while (0)

        f32x4 acc[2][4];
#pragma unroll
        for (int i = 0; i < 2; ++i)
#pragma unroll
            for (int j = 0; j < 4; ++j) acc[i][j] = (f32x4){0.f, 0.f, 0.f, 0.f};

        STAGE_O(0, 0);
        __syncthreads();

#pragma unroll 1
        for (int k0 = 0; k0 < K; k0 += 64) {
            int cur = (k0 >> 6) & 1;
            if (k0 + 64 < K) STAGE_O(cur ^ 1, k0 + 64);
            bf16x8 af[2][2], bfv[4][2];
#pragma unroll
            for (int i = 0; i < 2; ++i)
#pragma unroll
                for (int kk = 0; kk < 2; ++kk)
                    af[i][kk] = *(const bf16x8*)&sA[cur][wr + i * 16 + fr][((kk * 4 + fg) ^ csw) * 8];
#pragma unroll
            for (int j = 0; j < 4; ++j)
#pragma unroll
                for (int kk = 0; kk < 2; ++kk)
                    bfv[j][kk] = *(const bf16x8*)&sB[cur][wc + j * 16 + fr][((kk * 4 + fg) ^ csw) * 8];
#pragma unroll
            for (int i = 0; i < 2; ++i)
#pragma unroll
                for (int j = 0; j < 4; ++j) {
                    acc[i][j] = __builtin_amdgcn_mfma_f32_16x16x32_bf16(af[i][0], bfv[j][0], acc[i][j], 0, 0, 0);
                    acc[i][j] = __builtin_amdgcn_mfma_f32_16x16x32_bf16(af[i][1], bfv[j][1], acc[i][j], 0, 0, 0);
                }
            __syncthreads();
        }
#undef STAGE_O

        int rb = (lane >> 4) * 4;
#pragma unroll
        for (int j = 0; j < 4; ++j) {
            int n = bn + wc + j * 16 + fr;
            float bia = bias[n];
#pragma unroll
            for (int i = 0; i < 2; ++i)
#pragma unroll
                for (int r = 0; r < 4; ++r) {
                    int m = bm + wr + i * 16 + rb + r;
                    outp[(size_t)m * 1024 + n] = acc[i][j][r] + bia;
                }
        }
    } else {
        // ------------------- attn_out2 role (rid in [0,1024)) ----------------
        unsigned short (*sQ)[32][64]  = (unsigned short(*)[32][64])smem;            // 8 KB
        unsigned short (*sK)[128][64] = (unsigned short(*)[128][64])(smem + 8192);  // 32 KB
        float (*sM)[32]  = (float(*)[32])(smem + 40960);                            // 2 KB
        float (*sLi)[32] = (float(*)[32])(smem + 43008);                            // 2 KB

        int q0 = (rid & 31) * 32;
        int kc = ((rid >> 5) & 7) * 128;
        int b  = rid >> 8;

        for (int i = tid; i < 512; i += 256) {
            int h = i >> 5, qq = i & 31;
            sM[h][qq]  = mstats[(size_t)(b * Hh + h) * Lq + q0 + qq];
            sLi[h][qq] = lstats[(size_t)(b * Hh + h) * Lq + q0 + qq];
        }

#define STAGEH(BUF, H) do {                                                      \
    const unsigned short* Qp_ = Qh + ((size_t)(b * Hh + (H))) * Lq * Dd;         \
    const unsigned short* Kp_ = Kh + ((size_t)(b * Hh + (H))) * Lq * Dd;         \
    GLOAD_LDS16(Qp_ + (size_t)(q0 + w * 8 + srl) * Dd + scb * 8, &sQ[BUF][w * 8][0]); \
    _Pragma("unroll")                                                            \
    for (int i = 0; i < 4; ++i)                                                  \
        GLOAD_LDS16(Kp_ + (size_t)(kc + w * 32 + i * 8 + srl) * Dd + scb * 8,    \
                    &sK[BUF][w * 32 + i * 8][0]);                                \
} while (0)

#define RDH(AQ, BKk, BUF) do {                                                   \
    _Pragma("unroll")                                                            \
    for (int rt = 0; rt < 2; ++rt)                                               \
        _Pragma("unroll")                                                        \
        for (int ks = 0; ks < 2; ++ks)                                           \
            AQ[rt][ks] = *(const bf16x8*)&sQ[BUF][rt * 16 + fr][((ks * 4 + fg) ^ csw) * 8]; \
    _Pragma("unroll")                                                            \
    for (int ct = 0; ct < 2; ++ct)                                               \
        _Pragma("unroll")                                                        \
        for (int ks = 0; ks < 2; ++ks)                                           \
            BKk[ct][ks] = *(const bf16x8*)&sK[BUF][w * 32 + ct * 16 + fr][((ks * 4 + fg) ^ csw) * 8]; \
} while (0)

#define COMPH(AQ, BKk, H) do {                                                   \
    float4 mrow[2], lirow[2];                                                    \
    _Pragma("unroll")                                                            \
    for (int rt = 0; rt < 2; ++rt) {                                             \
        mrow[rt]  = *(const float4*)&sM[(H)][rt * 16 + fg * 4];                  \
        lirow[rt] = *(const float4*)&sLi[(H)][rt * 16 + fg * 4];                 \
    }                                                                            \
    _Pragma("unroll")                                                            \
    for (int rt = 0; rt < 2; ++rt)                                               \
        _Pragma("unroll")                                                        \
        for (int ct = 0; ct < 2; ++ct) {                                         \
            f32x4 binit = ct ? (f32x4){bias1,bias1,bias1,bias1}                  \
                             : (f32x4){bias0,bias0,bias0,bias0};                 \
            f32x4 s_ = __builtin_amdgcn_mfma_f32_16x16x32_bf16(AQ[rt][0], BKk[ct][0], binit, 0, 0, 0); \
            s_ = __builtin_amdgcn_mfma_f32_16x16x32_bf16(AQ[rt][1], BKk[ct][1], s_, 0, 0, 0); \
            _Pragma("unroll")                                                    \
            for (int r = 0; r < 4; ++r)                                          \
                o2[rt][ct][r] += __expf(s_[r] - mrow[rt][r]) * lirow[rt][r];     \
        }                                                                        \
} while (0)

        float bias0 = mbias[b * Lq + kc + w * 32 + fr];
        float bias1 = mbias[b * Lq + kc + w * 32 + 16 + fr];

        float o2[2][2][4];
#pragma unroll
        for (int rt = 0; rt < 2; ++rt)
#pragma unroll
            for (int ct = 0; ct < 2; ++ct)
#pragma unroll
                for (int r = 0; r < 4; ++r) o2[rt][ct][r] = 0.f;

        STAGEH(0, 0);
        __syncthreads();

#pragma unroll 1
        for (int h = 0; h < Hh; ++h) {
            int cur = h & 1;
            if (h < Hh - 1) STAGEH(cur ^ 1, h + 1);
            bf16x8 aq[2][2], bk[2][2];
            RDH(aq, bk, cur);
            COMPH(aq, bk, h);
            __syncthreads();
        }
#undef STAGEH
#undef RDH
#undef COMPH

#pragma unroll
        for (int rt = 0; rt < 2; ++rt)
#pragma unroll
            for (int ct = 0; ct < 2; ++ct)
#pragma unroll
                for (int r = 0; r < 4; ++r)
                    out2[((size_t)(b * Lq + q0 + rt * 16 + fg * 4 + r)) * Lq + kc + w * 32 + ct * 16 + fr]
                        = o2[rt][ct][r] * 0.0625f;
    }
}

// ---------------------------------------------------------------------------
extern "C" void kernel_launch(void* const* d_in, const int* in_sizes, int n_in,
                              void* d_out, int out_size, void* d_ws, size_t ws_size,
                              hipStream_t stream)
{
    const float* query = (const float*)d_in[0];
    const float* key   = (const float*)d_in[1];
    const float* value = (const float*)d_in[2];
    const float* amask = (const float*)d_in[3];
    const int*   kpm   = (const int*)d_in[4];
    const float* Wq = (const float*)d_in[5];
    const float* bq = (const float*)d_in[6];
    const float* Wk = (const float*)d_in[7];
    const float* bk = (const float*)d_in[8];
    const float* Wv = (const float*)d_in[9];
    const float* bv = (const float*)d_in[10];
    const float* Wo = (const float*)d_in[11];
    const float* bo = (const float*)d_in[12];

    float* out1 = (float*)d_out;                       // (B,L,E) f32
    float* out2 = out1 + (size_t)Bsz * Lq * Emb;       // (B,L,L) f32

    const size_t MB = 1u << 20;
    char* ws = (char*)d_ws;
    unsigned short* qbf = (unsigned short*)(ws + 0 * MB);
    unsigned short* kbf = (unsigned short*)(ws + 8 * MB);
    unsigned short* vbf = (unsigned short*)(ws + 16 * MB);
    unsigned short* wqb = (unsigned short*)(ws + 24 * MB);
    unsigned short* wkb = (unsigned short*)(ws + 26 * MB);
    unsigned short* wvb = (unsigned short*)(ws + 28 * MB);
    unsigned short* wob = (unsigned short*)(ws + 30 * MB);
    unsigned short* QhB = (unsigned short*)(ws + 32 * MB);  // (B,H,L,D) bf16 (pre-scaled x0.125)
    unsigned short* KhB = (unsigned short*)(ws + 40 * MB);
    unsigned short* VtB = (unsigned short*)(ws + 48 * MB);  // (B,H,D,L) bf16
    unsigned short* ctxB = (unsigned short*)(ws + 56 * MB); // (B,L,E) bf16
    float* mbias  = (float*)(ws + 64 * MB);                 // 16 KB
    // stats in a dedicated region (ws+17MB, proven in r17/r18): single writer
    // (attn_flash), no aliasing with any other buffer in the pipeline.
    float* mstats = (float*)(ws + 17 * MB);                 // 256 KB
    float* lstats = (float*)(ws + 17 * MB + 256 * 1024);    // 256 KB

    cvt_all<<<16400, 256, 0, stream>>>(query, key, value, Wq, Wk, Wv, Wo,
                                       qbf, kbf, vbf, wqb, wkb, wvb, wob,
                                       amask, kpm, mbias);

    gemm_qkv<<<1536, 256, 0, stream>>>(qbf, kbf, vbf, wqb, wkb, wvb,
                                       bq, bk, bv, QhB, KhB, VtB);

    attn_flash<<<512, 256, 0, stream>>>(QhB, KhB, VtB, mbias, ctxB, mstats, lstats);

    tail_fused<<<1536, 256, 0, stream>>>(ctxB, wob, bo, out1,
                                         QhB, KhB, mbias, mstats, lstats, out2);
}